// Round 12
// baseline (167.452 us; speedup 1.0000x reference)
//
#include <hip/hip_runtime.h>
#include <hip/hip_bf16.h>

#define N_NODES 50000
#define N_EDGES 800000
#define IN_FEAT 128
#define HIDDEN  256
#define OUT_F   64
#define M_PAD   50048   // 782 * 64
#define CONV_NB 1024    // convert_x block range
#define GATH_NB 2048
#define NGROUPS 12500   // N_NODES/4 node-groups
#define BSH     7       // bucket = dst >> 7  (128 nodes per bucket)
#define NBUCK   391     // ceil(50000/128)
#define NCHUNK  256     // edge chunks for hist/reorder
#define BCAP    4096    // max edges per bucket (mean 2046, sigma ~45)

typedef __attribute__((ext_vector_type(8))) short short8;
typedef __attribute__((ext_vector_type(4))) float f32x4;

static __device__ __forceinline__ unsigned short f2bf(float f) {
    unsigned u = __float_as_uint(f);
    unsigned r = (u + 0x7fffu + ((u >> 16) & 1u)) >> 16;   // RNE
    return (unsigned short)r;
}
static __device__ __forceinline__ float bflo(unsigned u) { return __uint_as_float(u << 16); }
static __device__ __forceinline__ float bfhi(unsigned u) { return __uint_as_float(u & 0xffff0000u); }

// ---- K1: per-chunk bucket hist (LDS) | convert x -> xbf bf16 | weight frag prep ----
__global__ __launch_bounds__(256) void bhcp_k(const int* __restrict__ dst,
                                              int* __restrict__ bh,
                                              const float* __restrict__ x,
                                              unsigned int* __restrict__ xbf_u,
                                              const float* __restrict__ W1l,
                                              const float* __restrict__ W1r,
                                              unsigned int* __restrict__ Wf1,
                                              const float* __restrict__ W2l,
                                              const float* __restrict__ W2r,
                                              unsigned int* __restrict__ Wf2) {
    __shared__ int hist[NBUCK];
    int b = blockIdx.x, t = threadIdx.x;
    if (b < NCHUNK) {
        for (int i = t; i < NBUCK; i += 256) hist[i] = 0;
        __syncthreads();
        for (int e = b * 256 + t; e < N_EDGES; e += NCHUNK * 256)
            atomicAdd(&hist[dst[e] >> BSH], 1);
        __syncthreads();
        for (int i = t; i < NBUCK; i += 256) bh[b * NBUCK + i] = hist[i];
    } else if (b < NCHUNK + CONV_NB) {
        const int T = CONV_NB * 256;
        for (int i = (b - NCHUNK) * 256 + t; i < N_NODES * 64; i += T) {
            int n = i >> 6, p = i & 63;
            float2 v = ((const float2*)(x + (size_t)n * IN_FEAT))[p];
            xbf_u[(size_t)n * 64 + p] = (unsigned)f2bf(v.x) | ((unsigned)f2bf(v.y) << 16);
        }
    } else if (b < NCHUNK + CONV_NB + 128) {
        int i = (b - NCHUNK - CONV_NB) * 256 + t;   // < 32768 u32
        int s = i * 2;
        int j = s & 7, lane = (s >> 3) & 63, nt = (s >> 9) & 15, ks = s >> 13;
        int n = nt * 16 + (lane & 15);
        int k = ks * 32 + ((lane >> 4) << 3) + j;
        float v0, v1;
        if (k < 128) { v0 = W1l[n * 128 + k];       v1 = W1l[n * 128 + k + 1]; }
        else         { v0 = W1r[n * 128 + k - 128]; v1 = W1r[n * 128 + k - 127]; }
        Wf1[i] = (unsigned)f2bf(v0) | ((unsigned)f2bf(v1) << 16);
    } else {
        int i = (b - NCHUNK - CONV_NB - 128) * 256 + t;   // < 16384 u32
        int s = i * 2;
        int j = s & 7, lane = (s >> 3) & 63, nt = (s >> 9) & 7, ks = s >> 12;
        int n = nt * 16 + (lane & 15);
        int k = ks * 32 + ((lane >> 4) << 3) + j;
        float v0, v1;
        if (n < 64) { v0 = W2l[n * 256 + k];        v1 = W2l[n * 256 + k + 1]; }
        else        { v0 = W2r[(n - 64) * 256 + k]; v1 = W2r[(n - 64) * 256 + k + 1]; }
        Wf2[i] = (unsigned)f2bf(v0) | ((unsigned)f2bf(v1) << 16);
    }
}

// ---------------- K2: per-bucket scan over chunks -> obuf[chunk][bucket], btot ----------------
__global__ __launch_bounds__(256) void chunkscan_k(const int* __restrict__ bh,
                                                   int* __restrict__ obuf,
                                                   int* __restrict__ btot) {
    __shared__ int s[256];
    int q = blockIdx.x, t = threadIdx.x;
    int v = bh[t * NBUCK + q];
    s[t] = v;
    __syncthreads();
    for (int off = 1; off < 256; off <<= 1) {
        int add = (t >= off) ? s[t - off] : 0;
        __syncthreads();
        s[t] += add;
        __syncthreads();
    }
    obuf[t * NBUCK + q] = s[t] - v;   // exclusive within bucket
    if (t == 255) btot[q] = s[255];
}

// ---------------- K3: exclusive scan of bucket totals -> bbase ----------------
__global__ __launch_bounds__(512) void bucketscan_k(const int* __restrict__ btot,
                                                    int* __restrict__ bbase,
                                                    int* __restrict__ rowptr) {
    __shared__ int s[512];
    int t = threadIdx.x;
    int v = (t < NBUCK) ? btot[t] : 0;
    s[t] = v;
    __syncthreads();
    for (int off = 1; off < 512; off <<= 1) {
        int add = (t >= off) ? s[t - off] : 0;
        __syncthreads();
        s[t] += add;
        __syncthreads();
    }
    if (t < NBUCK) bbase[t] = s[t] - v;
    if (t == 0) { bbase[NBUCK] = N_EDGES; rowptr[N_NODES] = N_EDGES; }
}

// ---------------- K4: reorder edges into bucket-major ebuf (LDS cursors) ----------------
__global__ __launch_bounds__(256) void reorder_k(const int* __restrict__ dst,
                                                 const int* __restrict__ src,
                                                 const int* __restrict__ bbase,
                                                 const int* __restrict__ obuf,
                                                 int2* __restrict__ ebuf) {
    __shared__ int cur[NBUCK];
    int b = blockIdx.x, t = threadIdx.x;
    for (int i = t; i < NBUCK; i += 256) cur[i] = bbase[i] + obuf[b * NBUCK + i];
    __syncthreads();
    for (int e = b * 256 + t; e < N_EDGES; e += NCHUNK * 256) {
        int d = dst[e], sv = src[e];
        int pos = atomicAdd(&cur[d >> BSH], 1);
        ebuf[pos] = make_int2(sv, d);
    }
}

// ---------------- K5: per-bucket CSR build (LDS stage; coalesced rowptr/eids) ----------------
__global__ __launch_bounds__(256) void bucketcsr_k(const int2* __restrict__ ebuf,
                                                   const int* __restrict__ bbase,
                                                   int* __restrict__ rowptr,
                                                   int* __restrict__ eids) {
    __shared__ int2 ed[BCAP];
    __shared__ int cnt[128];
    __shared__ int s[256];
    __shared__ int cur[128];
    int b = blockIdx.x, t = threadIdx.x;
    int e0 = bbase[b], e1 = bbase[b + 1];
    int m = e1 - e0; if (m > BCAP) m = BCAP;
    int d0 = b << BSH;
    if (t < 128) cnt[t] = 0;
    for (int i = t; i < m; i += 256) ed[i] = ebuf[e0 + i];
    __syncthreads();
    for (int i = t; i < m; i += 256) atomicAdd(&cnt[ed[i].y - d0], 1);
    __syncthreads();
    s[t] = (t < 128) ? cnt[t] : 0;
    __syncthreads();
    for (int off = 1; off < 256; off <<= 1) {
        int add = (t >= off) ? s[t - off] : 0;
        __syncthreads();
        s[t] += add;
        __syncthreads();
    }
    if (t < 128) {
        int excl = s[t] - cnt[t];
        cur[t] = excl;
        int node = d0 + t;
        if (node < N_NODES) rowptr[node] = e0 + excl;
    }
    __syncthreads();
    for (int i = t; i < m; i += 256) {
        int pos = atomicAdd(&cur[ed[i].y - d0], 1);
        eids[e0 + pos] = ed[i].x;
    }
}

// ---- K6: FUSED gather-mean + MFMA GEMM1: h = relu([agg|x] @ W1cat^T + b1) ----
// 4 waves; phase 1: each wave gather-means 16 nodes into LDS (unroll-4 MLP);
// phase 2: 32x128 MFMA tile per wave, agg-half of A from LDS, x-half from xbf.
__global__ __launch_bounds__(256) void fused_gemm1_k(
        const unsigned short* __restrict__ xbf, const int* __restrict__ eids,
        const int* __restrict__ rowptr, const unsigned short* __restrict__ Wf,
        const float* __restrict__ b1, unsigned short* __restrict__ h) {
    __shared__ unsigned short aggs[64][128];   // 16 KB
    int wv = threadIdx.x >> 6, lane = threadIdx.x & 63;
    int eg = lane >> 4, cq = lane & 15;
    const uint4* Xq = (const uint4*)xbf;       // 16 uint4 per 128-bf16 row

    // ---- phase 1: gather-mean ----
    for (int it = 0; it < 16; it++) {
        int nl = wv * 16 + it;
        int node = blockIdx.x * 64 + nl;
        int b = 0, e = 0;
        if (node < N_NODES) { b = rowptr[node]; e = rowptr[node + 1]; }
        float a0 = 0.f, a1 = 0.f, a2 = 0.f, a3 = 0.f, a4 = 0.f, a5 = 0.f, a6 = 0.f, a7 = 0.f;
        int i = b + eg;
        for (; i + 12 < e; i += 16) {          // 4 edges in flight per lane
            int s0 = eids[i], s1 = eids[i + 4], s2 = eids[i + 8], s3 = eids[i + 12];
            uint4 v0 = Xq[(size_t)s0 * 16 + cq];
            uint4 v1 = Xq[(size_t)s1 * 16 + cq];
            uint4 v2 = Xq[(size_t)s2 * 16 + cq];
            uint4 v3 = Xq[(size_t)s3 * 16 + cq];
            a0 += bflo(v0.x) + bflo(v1.x) + bflo(v2.x) + bflo(v3.x);
            a1 += bfhi(v0.x) + bfhi(v1.x) + bfhi(v2.x) + bfhi(v3.x);
            a2 += bflo(v0.y) + bflo(v1.y) + bflo(v2.y) + bflo(v3.y);
            a3 += bfhi(v0.y) + bfhi(v1.y) + bfhi(v2.y) + bfhi(v3.y);
            a4 += bflo(v0.z) + bflo(v1.z) + bflo(v2.z) + bflo(v3.z);
            a5 += bfhi(v0.z) + bfhi(v1.z) + bfhi(v2.z) + bfhi(v3.z);
            a6 += bflo(v0.w) + bflo(v1.w) + bflo(v2.w) + bflo(v3.w);
            a7 += bfhi(v0.w) + bfhi(v1.w) + bfhi(v2.w) + bfhi(v3.w);
        }
        for (; i < e; i += 4) {
            int s = eids[i];
            uint4 v = Xq[(size_t)s * 16 + cq];
            a0 += bflo(v.x); a1 += bfhi(v.x);
            a2 += bflo(v.y); a3 += bfhi(v.y);
            a4 += bflo(v.z); a5 += bfhi(v.z);
            a6 += bflo(v.w); a7 += bfhi(v.w);
        }
#pragma unroll
        for (int m = 16; m <= 32; m <<= 1) {
            a0 += __shfl_xor(a0, m); a1 += __shfl_xor(a1, m);
            a2 += __shfl_xor(a2, m); a3 += __shfl_xor(a3, m);
            a4 += __shfl_xor(a4, m); a5 += __shfl_xor(a5, m);
            a6 += __shfl_xor(a6, m); a7 += __shfl_xor(a7, m);
        }
        if (eg == 0) {
            int deg = e - b; if (deg < 1) deg = 1;
            float inv = 1.f / (float)deg;
            uint4 r;
            r.x = (unsigned)f2bf(a0 * inv) | ((unsigned)f2bf(a1 * inv) << 16);
            r.y = (unsigned)f2bf(a2 * inv) | ((unsigned)f2bf(a3 * inv) << 16);
            r.z = (unsigned)f2bf(a4 * inv) | ((unsigned)f2bf(a5 * inv) << 16);
            r.w = (unsigned)f2bf(a6 * inv) | ((unsigned)f2bf(a7 * inv) << 16);
            ((uint4*)aggs[nl])[cq] = r;
        }
    }
    __syncthreads();

    // ---- phase 2: MFMA ----
    int rowh = wv >> 1, colh = wv & 1;
    int m0 = blockIdx.x * 64 + rowh * 32;
    int row = lane & 15, kg = lane >> 4;
    const short8* Wf8 = (const short8*)Wf;

    short8 af[2][8];
#pragma unroll
    for (int mt = 0; mt < 2; mt++) {
        const unsigned short* lr = &aggs[rowh * 32 + mt * 16 + row][kg * 8];
#pragma unroll
        for (int ks = 0; ks < 4; ks++) af[mt][ks] = *(const short8*)(lr + ks * 32);
        const unsigned short* gr = xbf + (size_t)(m0 + mt * 16 + row) * 128 + kg * 8;
#pragma unroll
        for (int ks = 0; ks < 4; ks++) af[mt][ks + 4] = *(const short8*)(gr + ks * 32);
    }
    f32x4 acc[2][8];
#pragma unroll
    for (int mt = 0; mt < 2; mt++)
#pragma unroll
        for (int nt = 0; nt < 8; nt++) acc[mt][nt] = (f32x4)(0.f);

#pragma unroll
    for (int ks = 0; ks < 8; ks++) {
        short8 bf[8];
#pragma unroll
        for (int nt = 0; nt < 8; nt++)
            bf[nt] = Wf8[(ks * 16 + colh * 8 + nt) * 64 + lane];
#pragma unroll
        for (int nt = 0; nt < 8; nt++) {
#pragma unroll
            for (int mt = 0; mt < 2; mt++)
                acc[mt][nt] = __builtin_amdgcn_mfma_f32_16x16x32_bf16(af[mt][ks], bf[nt],
                                                                      acc[mt][nt], 0, 0, 0);
        }
    }

#pragma unroll
    for (int mt = 0; mt < 2; mt++) {
        int r0 = m0 + mt * 16 + kg * 4;
#pragma unroll
        for (int nt = 0; nt < 8; nt++) {
            int c = colh * 128 + nt * 16 + row;
            float bias = b1[c];
#pragma unroll
            for (int i = 0; i < 4; i++) {
                float v = acc[mt][nt][i] + bias;
                v = v > 0.f ? v : 0.f;
                h[(size_t)(r0 + i) * 256 + c] = f2bf(v);
            }
        }
    }
}

// ---------------- MFMA GEMM2: [y | out_r] = h @ W2cat^T, M=M_PAD N=128 K=256 ----------------
__global__ __launch_bounds__(256) void mfma_gemm2_k(
        const unsigned short* __restrict__ A, const unsigned short* __restrict__ Wf,
        const float* __restrict__ b2, unsigned short* __restrict__ y,
        float* __restrict__ out) {
    int wv = threadIdx.x >> 6, lane = threadIdx.x & 63;
    int m0 = blockIdx.x * 128 + wv * 32;
    int row = lane & 15, kg = lane >> 4;
    const short8* Wf8 = (const short8*)Wf;

    short8 af[2][8];
#pragma unroll
    for (int mt = 0; mt < 2; mt++) {
        const short8* ar = (const short8*)(A + (size_t)(m0 + mt * 16 + row) * 256 + kg * 8);
#pragma unroll
        for (int ks = 0; ks < 8; ks++) af[mt][ks] = ar[ks * 4];
    }
    f32x4 acc[2][8];
#pragma unroll
    for (int mt = 0; mt < 2; mt++)
#pragma unroll
        for (int nt = 0; nt < 8; nt++) acc[mt][nt] = (f32x4)(0.f);

#pragma unroll
    for (int ks = 0; ks < 8; ks++) {
        short8 bf[8];
#pragma unroll
        for (int nt = 0; nt < 8; nt++)
            bf[nt] = Wf8[(ks * 8 + nt) * 64 + lane];
#pragma unroll
        for (int nt = 0; nt < 8; nt++) {
#pragma unroll
            for (int mt = 0; mt < 2; mt++)
                acc[mt][nt] = __builtin_amdgcn_mfma_f32_16x16x32_bf16(af[mt][ks], bf[nt],
                                                                      acc[mt][nt], 0, 0, 0);
        }
    }

#pragma unroll
    for (int mt = 0; mt < 2; mt++) {
        int r0 = m0 + mt * 16 + kg * 4;
#pragma unroll
        for (int nt = 0; nt < 8; nt++) {
            int c = nt * 16 + row;   // 0..127
#pragma unroll
            for (int i = 0; i < 4; i++) {
                int rr = r0 + i;
                if (nt < 4) {
                    y[(size_t)rr * OUT_F + c] = f2bf(acc[mt][nt][i]);
                } else if (rr < N_NODES) {
                    out[(size_t)rr * OUT_F + (c - 64)] = acc[mt][nt][i] + b2[c - 64];
                }
            }
        }
    }
}

// ---------------- gather-mean layer 2: 8 edges/iter + unroll-2, grid-stride ----------------
__global__ __launch_bounds__(256) void gather2_k(const unsigned int* __restrict__ yu,
                                                 const int* __restrict__ eids,
                                                 const int* __restrict__ rowptr,
                                                 float* __restrict__ out) {
    int w = threadIdx.x >> 6, lane = threadIdx.x & 63;
    int eg = lane >> 3, cq = lane & 7;
    for (int g = blockIdx.x; g < NGROUPS; g += GATH_NB) {
        int node = g * 4 + w;
        int b = rowptr[node], e = rowptr[node + 1];
        float a0 = 0.f, a1 = 0.f, a2 = 0.f, a3 = 0.f, a4 = 0.f, a5 = 0.f, a6 = 0.f, a7 = 0.f;
        int i = b + eg;
        for (; i + 8 < e; i += 16) {           // 2 edges in flight per lane
            int s0 = eids[i], s1 = eids[i + 8];
            uint4 v0 = ((const uint4*)(yu + (size_t)s0 * 32))[cq];
            uint4 v1 = ((const uint4*)(yu + (size_t)s1 * 32))[cq];
            a0 += bflo(v0.x) + bflo(v1.x); a1 += bfhi(v0.x) + bfhi(v1.x);
            a2 += bflo(v0.y) + bflo(v1.y); a3 += bfhi(v0.y) + bfhi(v1.y);
            a4 += bflo(v0.z) + bflo(v1.z); a5 += bfhi(v0.z) + bfhi(v1.z);
            a6 += bflo(v0.w) + bflo(v1.w); a7 += bfhi(v0.w) + bfhi(v1.w);
        }
        for (; i < e; i += 8) {
            int s = eids[i];
            uint4 v = ((const uint4*)(yu + (size_t)s * 32))[cq];
            a0 += bflo(v.x); a1 += bfhi(v.x);
            a2 += bflo(v.y); a3 += bfhi(v.y);
            a4 += bflo(v.z); a5 += bfhi(v.z);
            a6 += bflo(v.w); a7 += bfhi(v.w);
        }
#pragma unroll
        for (int m = 8; m <= 32; m <<= 1) {
            a0 += __shfl_xor(a0, m); a1 += __shfl_xor(a1, m);
            a2 += __shfl_xor(a2, m); a3 += __shfl_xor(a3, m);
            a4 += __shfl_xor(a4, m); a5 += __shfl_xor(a5, m);
            a6 += __shfl_xor(a6, m); a7 += __shfl_xor(a7, m);
        }
        if (eg == 0) {
            int deg = e - b; if (deg < 1) deg = 1;
            float inv = 1.f / (float)deg;
            float4* p = (float4*)(out + (size_t)node * OUT_F + cq * 8);
            float4 c0 = p[0], c1 = p[1];
            c0.x += a0 * inv; c0.y += a1 * inv; c0.z += a2 * inv; c0.w += a3 * inv;
            c1.x += a4 * inv; c1.y += a5 * inv; c1.z += a6 * inv; c1.w += a7 * inv;
            p[0] = c0; p[1] = c1;
        }
    }
}

extern "C" void kernel_launch(void* const* d_in, const int* in_sizes, int n_in,
                              void* d_out, int out_size, void* d_ws, size_t ws_size,
                              hipStream_t stream) {
    const float* x    = (const float*)d_in[0];
    const int*   eidx = (const int*)d_in[1];
    const float* W1l  = (const float*)d_in[2];
    const float* W1r  = (const float*)d_in[3];
    const float* b1   = (const float*)d_in[4];
    const float* W2l  = (const float*)d_in[5];
    const float* W2r  = (const float*)d_in[6];
    const float* b2   = (const float*)d_in[7];
    float* out = (float*)d_out;

    const int* src = eidx;             // edge_index[0]
    const int* dst = eidx + N_EDGES;   // edge_index[1]

    // workspace layout (ushort units; int area starts 8B-aligned)
    unsigned short* xbf  = (unsigned short*)d_ws;              // [M_PAD][128] bf16
    unsigned short* hbuf = xbf + (size_t)M_PAD * 128;          // [M_PAD][256] bf16
    unsigned short* ybuf = hbuf + (size_t)M_PAD * 256;         // [M_PAD][64]  bf16
    unsigned short* W1f  = ybuf + (size_t)M_PAD * OUT_F;       // 65536
    unsigned short* W2f  = W1f + 65536;                        // 32768
    int2* ebuf  = (int2*)(W2f + 32768);                        // 800000 int2
    int* rowptr = (int*)(ebuf + N_EDGES);                      // 50001
    int* eids   = rowptr + N_NODES + 1;                        // 800000
    int* bh     = eids + N_EDGES;                              // 256*391
    int* obuf   = bh + NCHUNK * NBUCK;                         // 256*391
    int* btot   = obuf + NCHUNK * NBUCK;                       // 391
    int* bbase  = btot + NBUCK;                                // 392

    // K1: bucket hist | x->bf16 | weight frag conversion (one launch)
    bhcp_k<<<NCHUNK + CONV_NB + 192, 256, 0, stream>>>(dst, bh, x, (unsigned int*)xbf,
                                                       W1l, W1r, (unsigned int*)W1f,
                                                       W2l, W2r, (unsigned int*)W2f);

    // CSR build, bucket-sorted (LDS atomics only)
    chunkscan_k<<<NBUCK, 256, 0, stream>>>(bh, obuf, btot);
    bucketscan_k<<<1, 512, 0, stream>>>(btot, bbase, rowptr);
    reorder_k<<<NCHUNK, 256, 0, stream>>>(dst, src, bbase, obuf, ebuf);
    bucketcsr_k<<<NBUCK, 256, 0, stream>>>(ebuf, bbase, rowptr, eids);

    // fused gather-mean + GEMM1 -> h (bf16)
    fused_gemm1_k<<<M_PAD / 64, 256, 0, stream>>>(xbf, eids, rowptr, W1f, b1, hbuf);

    // GEMM2 -> y (bf16), out_r + b2 (fp32)
    mfma_gemm2_k<<<M_PAD / 128, 256, 0, stream>>>(hbuf, W2f, b2, ybuf, out);

    // layer-2 aggregation
    gather2_k<<<GATH_NB, 256, 0, stream>>>((const unsigned int*)ybuf, eids, rowptr, out);
}

// Round 13
// 130.945 us; speedup vs baseline: 1.2788x; 1.2788x over previous
//
#include <hip/hip_runtime.h>
#include <hip/hip_bf16.h>

#define N_NODES 50000
#define N_EDGES 800000
#define IN_FEAT 128
#define HIDDEN  256
#define OUT_F   64
#define M_PAD   50048   // 782 * 64
#define CONV_NB 1024    // convert_x block range
#define GATH_NB 2048
#define NGROUPS 12500   // N_NODES/4 node-groups
#define BSH     7       // bucket = dst >> 7  (128 nodes per bucket)
#define NBUCK   391     // ceil(50000/128)
#define NCHUNK  256     // edge chunks for hist/reorder
#define BCAP    4096    // max edges per bucket (mean 2046, sigma ~45)

typedef __attribute__((ext_vector_type(8))) short short8;
typedef __attribute__((ext_vector_type(4))) float f32x4;

static __device__ __forceinline__ unsigned short f2bf(float f) {
    unsigned u = __float_as_uint(f);
    unsigned r = (u + 0x7fffu + ((u >> 16) & 1u)) >> 16;   // RNE
    return (unsigned short)r;
}
static __device__ __forceinline__ float bflo(unsigned u) { return __uint_as_float(u << 16); }
static __device__ __forceinline__ float bfhi(unsigned u) { return __uint_as_float(u & 0xffff0000u); }

// ---- K1: per-chunk bucket hist (LDS) | convert x -> A1[:,128:256] bf16 | weight prep ----
__global__ __launch_bounds__(256) void bhcp_k(const int* __restrict__ dst,
                                              int* __restrict__ bh,
                                              const float* __restrict__ x,
                                              unsigned int* __restrict__ A1u,
                                              const float* __restrict__ W1l,
                                              const float* __restrict__ W1r,
                                              unsigned int* __restrict__ Wf1,
                                              const float* __restrict__ W2l,
                                              const float* __restrict__ W2r,
                                              unsigned int* __restrict__ Wf2) {
    __shared__ int hist[NBUCK];
    int b = blockIdx.x, t = threadIdx.x;
    if (b < NCHUNK) {
        for (int i = t; i < NBUCK; i += 256) hist[i] = 0;
        __syncthreads();
        for (int e = b * 256 + t; e < N_EDGES; e += NCHUNK * 256)
            atomicAdd(&hist[dst[e] >> BSH], 1);
        __syncthreads();
        for (int i = t; i < NBUCK; i += 256) bh[b * NBUCK + i] = hist[i];
    } else if (b < NCHUNK + CONV_NB) {
        const int T = CONV_NB * 256;
        for (int i = (b - NCHUNK) * 256 + t; i < N_NODES * 64; i += T) {
            int n = i >> 6, p = i & 63;
            float2 v = ((const float2*)(x + (size_t)n * IN_FEAT))[p];
            A1u[(size_t)n * 128 + 64 + p] = (unsigned)f2bf(v.x) | ((unsigned)f2bf(v.y) << 16);
        }
    } else if (b < NCHUNK + CONV_NB + 128) {
        int i = (b - NCHUNK - CONV_NB) * 256 + t;   // < 32768 u32
        int s = i * 2;
        int j = s & 7, lane = (s >> 3) & 63, nt = (s >> 9) & 15, ks = s >> 13;
        int n = nt * 16 + (lane & 15);
        int k = ks * 32 + ((lane >> 4) << 3) + j;
        float v0, v1;
        if (k < 128) { v0 = W1l[n * 128 + k];       v1 = W1l[n * 128 + k + 1]; }
        else         { v0 = W1r[n * 128 + k - 128]; v1 = W1r[n * 128 + k - 127]; }
        Wf1[i] = (unsigned)f2bf(v0) | ((unsigned)f2bf(v1) << 16);
    } else {
        int i = (b - NCHUNK - CONV_NB - 128) * 256 + t;   // < 16384 u32
        int s = i * 2;
        int j = s & 7, lane = (s >> 3) & 63, nt = (s >> 9) & 7, ks = s >> 12;
        int n = nt * 16 + (lane & 15);
        int k = ks * 32 + ((lane >> 4) << 3) + j;
        float v0, v1;
        if (n < 64) { v0 = W2l[n * 256 + k];        v1 = W2l[n * 256 + k + 1]; }
        else        { v0 = W2r[(n - 64) * 256 + k]; v1 = W2r[(n - 64) * 256 + k + 1]; }
        Wf2[i] = (unsigned)f2bf(v0) | ((unsigned)f2bf(v1) << 16);
    }
}

// ---------------- K2: per-bucket scan over chunks -> obuf[chunk][bucket], btot ----------------
__global__ __launch_bounds__(256) void chunkscan_k(const int* __restrict__ bh,
                                                   int* __restrict__ obuf,
                                                   int* __restrict__ btot) {
    __shared__ int s[256];
    int q = blockIdx.x, t = threadIdx.x;
    int v = bh[t * NBUCK + q];
    s[t] = v;
    __syncthreads();
    for (int off = 1; off < 256; off <<= 1) {
        int add = (t >= off) ? s[t - off] : 0;
        __syncthreads();
        s[t] += add;
        __syncthreads();
    }
    obuf[t * NBUCK + q] = s[t] - v;   // exclusive within bucket
    if (t == 255) btot[q] = s[255];
}

// ---------------- K3: exclusive scan of bucket totals -> bbase ----------------
__global__ __launch_bounds__(512) void bucketscan_k(const int* __restrict__ btot,
                                                    int* __restrict__ bbase,
                                                    int* __restrict__ rowptr) {
    __shared__ int s[512];
    int t = threadIdx.x;
    int v = (t < NBUCK) ? btot[t] : 0;
    s[t] = v;
    __syncthreads();
    for (int off = 1; off < 512; off <<= 1) {
        int add = (t >= off) ? s[t - off] : 0;
        __syncthreads();
        s[t] += add;
        __syncthreads();
    }
    if (t < NBUCK) bbase[t] = s[t] - v;
    if (t == 0) { bbase[NBUCK] = N_EDGES; rowptr[N_NODES] = N_EDGES; }
}

// ---------------- K4: reorder edges into bucket-major ebuf (LDS cursors) ----------------
__global__ __launch_bounds__(256) void reorder_k(const int* __restrict__ dst,
                                                 const int* __restrict__ src,
                                                 const int* __restrict__ bbase,
                                                 const int* __restrict__ obuf,
                                                 int2* __restrict__ ebuf) {
    __shared__ int cur[NBUCK];
    int b = blockIdx.x, t = threadIdx.x;
    for (int i = t; i < NBUCK; i += 256) cur[i] = bbase[i] + obuf[b * NBUCK + i];
    __syncthreads();
    for (int e = b * 256 + t; e < N_EDGES; e += NCHUNK * 256) {
        int d = dst[e], sv = src[e];
        int pos = atomicAdd(&cur[d >> BSH], 1);
        ebuf[pos] = make_int2(sv, d);
    }
}

// ---------------- K5: per-bucket CSR build (LDS stage; coalesced rowptr/eids) ----------------
__global__ __launch_bounds__(256) void bucketcsr_k(const int2* __restrict__ ebuf,
                                                   const int* __restrict__ bbase,
                                                   int* __restrict__ rowptr,
                                                   int* __restrict__ eids) {
    __shared__ int2 ed[BCAP];
    __shared__ int cnt[128];
    __shared__ int s[256];
    __shared__ int cur[128];
    int b = blockIdx.x, t = threadIdx.x;
    int e0 = bbase[b], e1 = bbase[b + 1];
    int m = e1 - e0; if (m > BCAP) m = BCAP;
    int d0 = b << BSH;
    if (t < 128) cnt[t] = 0;
    for (int i = t; i < m; i += 256) ed[i] = ebuf[e0 + i];
    __syncthreads();
    for (int i = t; i < m; i += 256) atomicAdd(&cnt[ed[i].y - d0], 1);
    __syncthreads();
    s[t] = (t < 128) ? cnt[t] : 0;
    __syncthreads();
    for (int off = 1; off < 256; off <<= 1) {
        int add = (t >= off) ? s[t - off] : 0;
        __syncthreads();
        s[t] += add;
        __syncthreads();
    }
    if (t < 128) {
        int excl = s[t] - cnt[t];
        cur[t] = excl;
        int node = d0 + t;
        if (node < N_NODES) rowptr[node] = e0 + excl;
    }
    __syncthreads();
    for (int i = t; i < m; i += 256) {
        int pos = atomicAdd(&cur[ed[i].y - d0], 1);
        eids[e0 + pos] = ed[i].x;
    }
}

// ---- gather-mean layer 1: 4 edges/iter + unroll-4 MLP, dwordx4/lane, grid-stride ----
__global__ __launch_bounds__(256) void gather1_k(const unsigned int* __restrict__ Au,
                                                 const int* __restrict__ eids,
                                                 const int* __restrict__ rowptr,
                                                 unsigned int* __restrict__ Aw) {
    int w = threadIdx.x >> 6, lane = threadIdx.x & 63;
    int eg = lane >> 4, cq = lane & 15;
    for (int g = blockIdx.x; g < NGROUPS; g += GATH_NB) {
        int node = g * 4 + w;
        int b = rowptr[node], e = rowptr[node + 1];
        float a0 = 0.f, a1 = 0.f, a2 = 0.f, a3 = 0.f, a4 = 0.f, a5 = 0.f, a6 = 0.f, a7 = 0.f;
        int i = b + eg;
        for (; i + 12 < e; i += 16) {          // 4 independent row-loads in flight
            int s0 = eids[i], s1 = eids[i + 4], s2 = eids[i + 8], s3 = eids[i + 12];
            uint4 v0 = ((const uint4*)(Au + (size_t)s0 * 128 + 64))[cq];
            uint4 v1 = ((const uint4*)(Au + (size_t)s1 * 128 + 64))[cq];
            uint4 v2 = ((const uint4*)(Au + (size_t)s2 * 128 + 64))[cq];
            uint4 v3 = ((const uint4*)(Au + (size_t)s3 * 128 + 64))[cq];
            a0 += bflo(v0.x) + bflo(v1.x) + bflo(v2.x) + bflo(v3.x);
            a1 += bfhi(v0.x) + bfhi(v1.x) + bfhi(v2.x) + bfhi(v3.x);
            a2 += bflo(v0.y) + bflo(v1.y) + bflo(v2.y) + bflo(v3.y);
            a3 += bfhi(v0.y) + bfhi(v1.y) + bfhi(v2.y) + bfhi(v3.y);
            a4 += bflo(v0.z) + bflo(v1.z) + bflo(v2.z) + bflo(v3.z);
            a5 += bfhi(v0.z) + bfhi(v1.z) + bfhi(v2.z) + bfhi(v3.z);
            a6 += bflo(v0.w) + bflo(v1.w) + bflo(v2.w) + bflo(v3.w);
            a7 += bfhi(v0.w) + bfhi(v1.w) + bfhi(v2.w) + bfhi(v3.w);
        }
        for (; i < e; i += 4) {
            int s = eids[i];
            uint4 v = ((const uint4*)(Au + (size_t)s * 128 + 64))[cq];
            a0 += bflo(v.x); a1 += bfhi(v.x);
            a2 += bflo(v.y); a3 += bfhi(v.y);
            a4 += bflo(v.z); a5 += bfhi(v.z);
            a6 += bflo(v.w); a7 += bfhi(v.w);
        }
#pragma unroll
        for (int m = 16; m <= 32; m <<= 1) {
            a0 += __shfl_xor(a0, m); a1 += __shfl_xor(a1, m);
            a2 += __shfl_xor(a2, m); a3 += __shfl_xor(a3, m);
            a4 += __shfl_xor(a4, m); a5 += __shfl_xor(a5, m);
            a6 += __shfl_xor(a6, m); a7 += __shfl_xor(a7, m);
        }
        if (eg == 0) {
            int deg = e - b; if (deg < 1) deg = 1;
            float inv = 1.f / (float)deg;
            uint4 r;
            r.x = (unsigned)f2bf(a0 * inv) | ((unsigned)f2bf(a1 * inv) << 16);
            r.y = (unsigned)f2bf(a2 * inv) | ((unsigned)f2bf(a3 * inv) << 16);
            r.z = (unsigned)f2bf(a4 * inv) | ((unsigned)f2bf(a5 * inv) << 16);
            r.w = (unsigned)f2bf(a6 * inv) | ((unsigned)f2bf(a7 * inv) << 16);
            ((uint4*)(Aw + (size_t)node * 128))[cq] = r;
        }
    }
}

// ---------------- MFMA GEMM1: h = relu(A1 @ W1cat^T + b1), M=M_PAD N=256 K=256 ----------------
__global__ __launch_bounds__(256) void mfma_gemm1_k(
        const unsigned short* __restrict__ A, const unsigned short* __restrict__ Wf,
        const float* __restrict__ b1, unsigned short* __restrict__ h) {
    int wv = threadIdx.x >> 6, lane = threadIdx.x & 63;
    int rowh = wv >> 1, colh = wv & 1;
    int m0 = blockIdx.x * 64 + rowh * 32;
    int row = lane & 15, kg = lane >> 4;
    const short8* Wf8 = (const short8*)Wf;

    short8 af[2][8];
#pragma unroll
    for (int mt = 0; mt < 2; mt++) {
        const short8* ar = (const short8*)(A + (size_t)(m0 + mt * 16 + row) * 256 + kg * 8);
#pragma unroll
        for (int ks = 0; ks < 8; ks++) af[mt][ks] = ar[ks * 4];
    }
    f32x4 acc[2][8];
#pragma unroll
    for (int mt = 0; mt < 2; mt++)
#pragma unroll
        for (int nt = 0; nt < 8; nt++) acc[mt][nt] = (f32x4)(0.f);

#pragma unroll
    for (int ks = 0; ks < 8; ks++) {
        short8 bf[8];
#pragma unroll
        for (int nt = 0; nt < 8; nt++)
            bf[nt] = Wf8[(ks * 16 + colh * 8 + nt) * 64 + lane];
#pragma unroll
        for (int nt = 0; nt < 8; nt++) {
#pragma unroll
            for (int mt = 0; mt < 2; mt++)
                acc[mt][nt] = __builtin_amdgcn_mfma_f32_16x16x32_bf16(af[mt][ks], bf[nt],
                                                                      acc[mt][nt], 0, 0, 0);
        }
    }

#pragma unroll
    for (int mt = 0; mt < 2; mt++) {
        int r0 = m0 + mt * 16 + kg * 4;
#pragma unroll
        for (int nt = 0; nt < 8; nt++) {
            int c = colh * 128 + nt * 16 + row;
            float bias = b1[c];
#pragma unroll
            for (int i = 0; i < 4; i++) {
                float v = acc[mt][nt][i] + bias;
                v = v > 0.f ? v : 0.f;
                h[(size_t)(r0 + i) * 256 + c] = f2bf(v);
            }
        }
    }
}

// ---------------- MFMA GEMM2: [y | out_r] = h @ W2cat^T, M=M_PAD N=128 K=256 ----------------
__global__ __launch_bounds__(256) void mfma_gemm2_k(
        const unsigned short* __restrict__ A, const unsigned short* __restrict__ Wf,
        const float* __restrict__ b2, unsigned short* __restrict__ y,
        float* __restrict__ out) {
    int wv = threadIdx.x >> 6, lane = threadIdx.x & 63;
    int m0 = blockIdx.x * 128 + wv * 32;
    int row = lane & 15, kg = lane >> 4;
    const short8* Wf8 = (const short8*)Wf;

    short8 af[2][8];
#pragma unroll
    for (int mt = 0; mt < 2; mt++) {
        const short8* ar = (const short8*)(A + (size_t)(m0 + mt * 16 + row) * 256 + kg * 8);
#pragma unroll
        for (int ks = 0; ks < 8; ks++) af[mt][ks] = ar[ks * 4];
    }
    f32x4 acc[2][8];
#pragma unroll
    for (int mt = 0; mt < 2; mt++)
#pragma unroll
        for (int nt = 0; nt < 8; nt++) acc[mt][nt] = (f32x4)(0.f);

#pragma unroll
    for (int ks = 0; ks < 8; ks++) {
        short8 bf[8];
#pragma unroll
        for (int nt = 0; nt < 8; nt++)
            bf[nt] = Wf8[(ks * 8 + nt) * 64 + lane];
#pragma unroll
        for (int nt = 0; nt < 8; nt++) {
#pragma unroll
            for (int mt = 0; mt < 2; mt++)
                acc[mt][nt] = __builtin_amdgcn_mfma_f32_16x16x32_bf16(af[mt][ks], bf[nt],
                                                                      acc[mt][nt], 0, 0, 0);
        }
    }

#pragma unroll
    for (int mt = 0; mt < 2; mt++) {
        int r0 = m0 + mt * 16 + kg * 4;
#pragma unroll
        for (int nt = 0; nt < 8; nt++) {
            int c = nt * 16 + row;   // 0..127
#pragma unroll
            for (int i = 0; i < 4; i++) {
                int rr = r0 + i;
                if (nt < 4) {
                    y[(size_t)rr * OUT_F + c] = f2bf(acc[mt][nt][i]);
                } else if (rr < N_NODES) {
                    out[(size_t)rr * OUT_F + (c - 64)] = acc[mt][nt][i] + b2[c - 64];
                }
            }
        }
    }
}

// ---------------- gather-mean layer 2: 8 edges/iter + unroll-2, grid-stride ----------------
__global__ __launch_bounds__(256) void gather2_k(const unsigned int* __restrict__ yu,
                                                 const int* __restrict__ eids,
                                                 const int* __restrict__ rowptr,
                                                 float* __restrict__ out) {
    int w = threadIdx.x >> 6, lane = threadIdx.x & 63;
    int eg = lane >> 3, cq = lane & 7;
    for (int g = blockIdx.x; g < NGROUPS; g += GATH_NB) {
        int node = g * 4 + w;
        int b = rowptr[node], e = rowptr[node + 1];
        float a0 = 0.f, a1 = 0.f, a2 = 0.f, a3 = 0.f, a4 = 0.f, a5 = 0.f, a6 = 0.f, a7 = 0.f;
        int i = b + eg;
        for (; i + 8 < e; i += 16) {           // 2 edges in flight per lane
            int s0 = eids[i], s1 = eids[i + 8];
            uint4 v0 = ((const uint4*)(yu + (size_t)s0 * 32))[cq];
            uint4 v1 = ((const uint4*)(yu + (size_t)s1 * 32))[cq];
            a0 += bflo(v0.x) + bflo(v1.x); a1 += bfhi(v0.x) + bfhi(v1.x);
            a2 += bflo(v0.y) + bflo(v1.y); a3 += bfhi(v0.y) + bfhi(v1.y);
            a4 += bflo(v0.z) + bflo(v1.z); a5 += bfhi(v0.z) + bfhi(v1.z);
            a6 += bflo(v0.w) + bflo(v1.w); a7 += bfhi(v0.w) + bfhi(v1.w);
        }
        for (; i < e; i += 8) {
            int s = eids[i];
            uint4 v = ((const uint4*)(yu + (size_t)s * 32))[cq];
            a0 += bflo(v.x); a1 += bfhi(v.x);
            a2 += bflo(v.y); a3 += bfhi(v.y);
            a4 += bflo(v.z); a5 += bfhi(v.z);
            a6 += bflo(v.w); a7 += bfhi(v.w);
        }
#pragma unroll
        for (int m = 8; m <= 32; m <<= 1) {
            a0 += __shfl_xor(a0, m); a1 += __shfl_xor(a1, m);
            a2 += __shfl_xor(a2, m); a3 += __shfl_xor(a3, m);
            a4 += __shfl_xor(a4, m); a5 += __shfl_xor(a5, m);
            a6 += __shfl_xor(a6, m); a7 += __shfl_xor(a7, m);
        }
        if (eg == 0) {
            int deg = e - b; if (deg < 1) deg = 1;
            float inv = 1.f / (float)deg;
            float4* p = (float4*)(out + (size_t)node * OUT_F + cq * 8);
            float4 c0 = p[0], c1 = p[1];
            c0.x += a0 * inv; c0.y += a1 * inv; c0.z += a2 * inv; c0.w += a3 * inv;
            c1.x += a4 * inv; c1.y += a5 * inv; c1.z += a6 * inv; c1.w += a7 * inv;
            p[0] = c0; p[1] = c1;
        }
    }
}

extern "C" void kernel_launch(void* const* d_in, const int* in_sizes, int n_in,
                              void* d_out, int out_size, void* d_ws, size_t ws_size,
                              hipStream_t stream) {
    const float* x    = (const float*)d_in[0];
    const int*   eidx = (const int*)d_in[1];
    const float* W1l  = (const float*)d_in[2];
    const float* W1r  = (const float*)d_in[3];
    const float* b1   = (const float*)d_in[4];
    const float* W2l  = (const float*)d_in[5];
    const float* W2r  = (const float*)d_in[6];
    const float* b2   = (const float*)d_in[7];
    float* out = (float*)d_out;

    const int* src = eidx;             // edge_index[0]
    const int* dst = eidx + N_EDGES;   // edge_index[1]

    // workspace layout (ushort units; int area starts 8B-aligned)
    unsigned short* A1   = (unsigned short*)d_ws;              // [M_PAD][256] bf16
    unsigned short* hbuf = A1 + (size_t)M_PAD * 256;           // [M_PAD][256] bf16
    unsigned short* ybuf = hbuf + (size_t)M_PAD * 256;         // [M_PAD][64]  bf16
    unsigned short* W1f  = ybuf + (size_t)M_PAD * OUT_F;       // 65536
    unsigned short* W2f  = W1f + 65536;                        // 32768
    int2* ebuf  = (int2*)(W2f + 32768);                        // 800000 int2
    int* rowptr = (int*)(ebuf + N_EDGES);                      // 50001
    int* eids   = rowptr + N_NODES + 1;                        // 800000
    int* bh     = eids + N_EDGES;                              // 256*391
    int* obuf   = bh + NCHUNK * NBUCK;                         // 256*391
    int* btot   = obuf + NCHUNK * NBUCK;                       // 391
    int* bbase  = btot + NBUCK;                                // 392

    // K1: bucket hist | x->bf16 into A1 | weight frag conversion (one launch)
    bhcp_k<<<NCHUNK + CONV_NB + 192, 256, 0, stream>>>(dst, bh, x, (unsigned int*)A1,
                                                       W1l, W1r, (unsigned int*)W1f,
                                                       W2l, W2r, (unsigned int*)W2f);

    // CSR build, bucket-sorted (LDS atomics only)
    chunkscan_k<<<NBUCK, 256, 0, stream>>>(bh, obuf, btot);
    bucketscan_k<<<1, 512, 0, stream>>>(btot, bbase, rowptr);
    reorder_k<<<NCHUNK, 256, 0, stream>>>(dst, src, bbase, obuf, ebuf);
    bucketcsr_k<<<NBUCK, 256, 0, stream>>>(ebuf, bbase, rowptr, eids);

    // layer-1 aggregation (unroll-4 MLP)
    gather1_k<<<GATH_NB, 256, 0, stream>>>((const unsigned int*)A1, eids, rowptr,
                                           (unsigned int*)A1);

    // GEMM1 -> h (bf16)
    mfma_gemm1_k<<<M_PAD / 64, 256, 0, stream>>>(A1, W1f, b1, hbuf);

    // GEMM2 -> y (bf16), out_r + b2 (fp32)
    mfma_gemm2_k<<<M_PAD / 128, 256, 0, stream>>>(hbuf, W2f, b2, ybuf, out);

    // layer-2 aggregation (unroll-2)
    gather2_k<<<GATH_NB, 256, 0, stream>>>((const unsigned int*)ybuf, eids, rowptr, out);
}